// Round 1
// 453.796 us; speedup vs baseline: 1.1293x; 1.1293x over previous
//
#include <hip/hip_runtime.h>

// UAG_RNN v5: latency-focused rewrite of the two scan kernels.
//  - colscan: 256 threads / 4 waves (2 row-groups per wave) -> 512-VGPR budget;
//    bias C-inits + weights + double-buffered prefetch all register-resident;
//    lgkm-only barriers (raw s_barrier) so global loads/stores stay in flight
//    across steps (T4 counted-vmcnt via compiler); ping-pong prefetch sets.
//  - rowscan: single wave -> all barriers removed; ping-pong prefetch sets;
//    bias hoisted; __launch_bounds__(64,1) for full register budget.
// B=8, C=64, H=128, W=128.

#define B_ 8
#define C_ 64
#define H_ 128
#define W_ 128
#define HW_ (H_*W_)      // 16384
#define CHW_ (C_*HW_)    // 1048576
#define TOT_ (B_*CHW_)   // 8388608

typedef __attribute__((ext_vector_type(8))) short bfrag;
typedef __attribute__((ext_vector_type(4))) float f4_t;

__device__ inline unsigned short bfr(float f) {
    unsigned int u = __float_as_uint(f);
    u += 0x7fffu + ((u >> 16) & 1u);
    return (unsigned short)(u >> 16);
}
__device__ inline float b2f(unsigned short u) {
    return __uint_as_float(((unsigned int)u) << 16);
}
__device__ inline bfrag packf(float4 a, float4 b) {
    bfrag r;
    r[0]=(short)bfr(a.x); r[1]=(short)bfr(a.y); r[2]=(short)bfr(a.z); r[3]=(short)bfr(a.w);
    r[4]=(short)bfr(b.x); r[5]=(short)bfr(b.y); r[6]=(short)bfr(b.z); r[7]=(short)bfr(b.w);
    return r;
}
__device__ inline ushort4 pack4(float a, float b, float c, float d) {
    ushort4 r; r.x=bfr(a); r.y=bfr(b); r.z=bfr(c); r.w=bfr(d); return r;
}
__device__ inline unsigned int relu2(unsigned int w) {
    unsigned int lo = (w & 0x8000u) ? 0u : (w & 0xffffu);
    unsigned int hi = (w & 0x80000000u) ? 0u : (w & 0xffff0000u);
    return lo | hi;
}
__device__ inline uint4 relu8(uint4 v) {
    v.x = relu2(v.x); v.y = relu2(v.y); v.z = relu2(v.z); v.w = relu2(v.w);
    return v;
}

#define MFMA __builtin_amdgcn_mfma_f32_16x16x32_bf16

// lgkm-only barrier: LDS state exchange ordered; global loads/stores stay in
// flight across it (compiler inserts counted vmcnt at actual use).
#define SBAR_LGKM() do { \
    asm volatile("s_waitcnt lgkmcnt(0)" ::: "memory"); \
    __builtin_amdgcn_sched_barrier(0); \
    __builtin_amdgcn_s_barrier(); \
    __builtin_amdgcn_sched_barrier(0); \
} while (0)

// x NCHW fp32 -> x2 NHWC bf16 ; y NCHW fp32 -> y2 NHWC fp32
__global__ void k_prep(const float* __restrict__ x, const float* __restrict__ y,
                       float* __restrict__ y2, unsigned short* __restrict__ x2) {
    __shared__ float t[64][65];
    int blk = blockIdx.x;
    int isx = blk >> 11; blk &= 2047;
    int b = blk >> 8, hw0 = (blk & 255) * 64;
    int cq = threadIdx.x >> 6, lo = threadIdx.x & 63;
    const float* ip = (isx ? x : y) + (size_t)b * CHW_;
#pragma unroll
    for (int p = 0; p < 16; p++) {
        int c = p * 4 + cq;
        t[c][lo] = ip[(size_t)c * HW_ + hw0 + lo];
    }
    __syncthreads();
    if (isx) {
        unsigned short* op = x2 + (size_t)b * CHW_;
#pragma unroll
        for (int p = 0; p < 16; p++) {
            int hw = p * 4 + cq;
            op[(size_t)(hw0 + hw) * 64 + lo] = bfr(t[lo][hw]);
        }
    } else {
        float* op = y2 + (size_t)b * CHW_;
#pragma unroll
        for (int p = 0; p < 16; p++) {
            int hw = p * 4 + cq;
            op[(size_t)(hw0 + hw) * 64 + lo] = t[lo][hw];
        }
    }
}

// sum 4 fp32 NHWC dir buffers -> out NCHW fp32
__global__ void k_tb(const float* __restrict__ i0, const float* __restrict__ i1,
                     const float* __restrict__ i2, const float* __restrict__ i3,
                     float* __restrict__ outp) {
    __shared__ float t[64][65];
    int blk = blockIdx.x;
    int b = blk >> 8, hw0 = (blk & 255) * 64;
    int cq = threadIdx.x >> 6, lo = threadIdx.x & 63;
    size_t bb = (size_t)b * CHW_;
#pragma unroll
    for (int p = 0; p < 16; p++) {
        int hw = p * 4 + cq;
        size_t s = bb + (size_t)(hw0 + hw) * 64 + lo;
        t[hw][lo] = i0[s] + i1[s] + i2[s] + i3[s];
    }
    __syncthreads();
    float* op = outp + bb;
#pragma unroll
    for (int p = 0; p < 16; p++) {
        int c = p * 4 + cq;
        op[(size_t)c * HW_ + hw0 + lo] = t[lo][c];
    }
}

// ---------------- row scans ----------------
struct PrefR { uint4 x0, x1; float4 yv[4]; };

__device__ __forceinline__ void row_step(
        int i, int s, int w0, int q, int n,
        const unsigned short* __restrict__ xb, const float* __restrict__ yb,
        unsigned short* __restrict__ dT,
        unsigned short (&stt)[2][16][72],
        const bfrag (&WaF)[4][2], const bfrag (&WbF)[4][2],
        const f4_t (&cA)[4], const f4_t (&cB)[4],
        PrefR& cur, PrefR& nxt) {
    int row = s ? 127 - i : i;
    int rd = (i - 1) & 1, wr = i & 1;

    bfrag fb0 = *(const bfrag*)&stt[rd][n][q * 8];
    bfrag fb1 = *(const bfrag*)&stt[rd][n][32 + q * 8];
    bfrag fa0 = *(const bfrag*)&cur.x0;
    bfrag fa1 = *(const bfrag*)&cur.x1;

    f4_t DA[4], DB[4];
#pragma unroll
    for (int mt = 0; mt < 4; mt++) {
        DA[mt] = MFMA(WaF[mt][0], fa0, cA[mt], 0, 0, 0);
        DA[mt] = MFMA(WaF[mt][1], fa1, DA[mt], 0, 0, 0);
        DB[mt] = MFMA(WbF[mt][0], fb0, cB[mt], 0, 0, 0);
        DB[mt] = MFMA(WbF[mt][1], fb1, DB[mt], 0, 0, 0);
    }

    if (i < 127) {
        int rowN = s ? 126 - i : i + 1;
        int yrowN = s ? rowN + 1 : rowN - 1;
        const unsigned short* sp = xb + (size_t)(rowN * 128 + w0 + n) * 64 + q * 8;
        nxt.x0 = *(const uint4*)sp;
        nxt.x1 = *(const uint4*)(sp + 32);
#pragma unroll
        for (int mt = 0; mt < 4; mt++)
            nxt.yv[mt] = *(const float4*)&yb[(size_t)(yrowN * 128 + w0 + n) * 64 + mt * 16 + q * 4];
    }

#pragma unroll
    for (int mt = 0; mt < 4; mt++) {
        float h0 = fmaxf(DA[mt][0] + DB[mt][0] * cur.yv[mt].x, 0.f);
        float h1 = fmaxf(DA[mt][1] + DB[mt][1] * cur.yv[mt].y, 0.f);
        float h2 = fmaxf(DA[mt][2] + DB[mt][2] * cur.yv[mt].z, 0.f);
        float h3 = fmaxf(DA[mt][3] + DB[mt][3] * cur.yv[mt].w, 0.f);
        ushort4 pk = pack4(h0, h1, h2, h3);
        *(ushort4*)&stt[wr][n][mt * 16 + q * 4] = pk;
        *(ushort4*)&dT[(size_t)(row * 128 + w0 + n) * 64 + mt * 16 + q * 4] = pk;
    }
    // no barrier: single-wave block, compiler-inserted lgkmcnt orders LDS.
}

// grid 128 = s(2) x b(8) x wb(8 of width 16). 1 wave/block.
__global__ __launch_bounds__(64, 1) void k_rowscan(
        const unsigned short* __restrict__ x2, const float* __restrict__ y2,
        const float* __restrict__ Wc, const float* __restrict__ bc,
        unsigned short* __restrict__ hs2, unsigned short* __restrict__ hn2) {
    int bid = blockIdx.x;
    int s = bid >> 6, b = (bid >> 3) & 7, wb = bid & 7;
    int w0 = wb * 16;
    int lane = threadIdx.x, q = lane >> 4, n = lane & 15;
    int ka = s ? 8 : 0, kb = ka + 1;

    bfrag WaF[4][2], WbF[4][2];
#pragma unroll
    for (int mt = 0; mt < 4; mt++)
#pragma unroll
        for (int kc = 0; kc < 2; kc++) {
            const float* wp = Wc + (size_t)(ka * 64 + mt * 16 + n) * 64 + kc * 32 + q * 8;
            WaF[mt][kc] = packf(*(const float4*)wp, *(const float4*)(wp + 4));
            const float* wq2 = Wc + (size_t)(kb * 64 + mt * 16 + n) * 64 + kc * 32 + q * 8;
            WbF[mt][kc] = packf(*(const float4*)wq2, *(const float4*)(wq2 + 4));
        }
    f4_t cA[4], cB[4];
#pragma unroll
    for (int mt = 0; mt < 4; mt++) {
        float4 ta = *(const float4*)&bc[ka * 64 + mt * 16 + q * 4];
        float4 tb = *(const float4*)&bc[kb * 64 + mt * 16 + q * 4];
        cA[mt] = f4_t{ta.x, ta.y, ta.z, ta.w};
        cB[mt] = f4_t{tb.x, tb.y, tb.z, tb.w};
    }

    const unsigned short* xb = x2 + (size_t)b * CHW_;
    const float* yb = y2 + (size_t)b * CHW_;
    unsigned short* dT = (s ? hn2 : hs2) + (size_t)b * CHW_;

    __shared__ __align__(16) unsigned short stt[2][16][72];

    int row0 = s ? 127 : 0;
    {
        const unsigned short* sp = xb + (size_t)(row0 * 128 + w0 + n) * 64 + q * 16;
        uint4 v0 = *(const uint4*)sp;
        uint4 v1 = *(const uint4*)(sp + 8);
        if (s) { v0 = relu8(v0); v1 = relu8(v1); }
        *(uint4*)&stt[0][n][q * 16] = v0;
        *(uint4*)&stt[0][n][q * 16 + 8] = v1;
        unsigned short* op = dT + (size_t)(row0 * 128 + w0 + n) * 64 + q * 16;
        *(uint4*)op = v0;
        *(uint4*)(op + 8) = v1;
    }

    PrefR Pa, Pb;
    {
        int row1 = s ? 126 : 1;
        const unsigned short* sp = xb + (size_t)(row1 * 128 + w0 + n) * 64 + q * 8;
        Pa.x0 = *(const uint4*)sp;
        Pa.x1 = *(const uint4*)(sp + 32);
#pragma unroll
        for (int mt = 0; mt < 4; mt++)
            Pa.yv[mt] = *(const float4*)&yb[(size_t)(row0 * 128 + w0 + n) * 64 + mt * 16 + q * 4];
    }

    for (int i = 1; i < 127; i += 2) {
        row_step(i,     s, w0, q, n, xb, yb, dT, stt, WaF, WbF, cA, cB, Pa, Pb);
        row_step(i + 1, s, w0, q, n, xb, yb, dT, stt, WaF, WbF, cA, cB, Pb, Pa);
    }
    row_step(127, s, w0, q, n, xb, yb, dT, stt, WaF, WbF, cA, cB, Pa, Pb);
}

// ---------------- col scans ----------------
struct PrefG { uint4 b0, b1; float4 yr[4]; };

__device__ __forceinline__ void col_group(
        int j, int flip, int row, int q, int rsh, int srow, float gT,
        const unsigned short* __restrict__ base2, const float* __restrict__ yB,
        float* __restrict__ oB,
        unsigned short (&stt)[2][130][72],
        const bfrag (&WA)[4][2], const bfrag (&WB)[4][2], const bfrag (&WT)[4][2],
        const f4_t (&cAr)[4], const f4_t (&cBr)[4], const f4_t (&cTr)[4],
        PrefG& cur, PrefG& nxt) {
    int cj = flip ? 127 - j : j;
    int yc = flip ? 128 - j : j - 1;   // y column gating this step (col of j-1)
    int rd = (j - 1) & 1, wr = j & 1;

    // ys loads for THIS step issued early (latency hidden under LDS reads+MFMA)
    float4 ys[4];
#pragma unroll
    for (int mt = 0; mt < 4; mt++)
        ys[mt] = *(const float4*)&yB[(size_t)(rsh * 128 + yc) * 64 + mt * 16 + q * 4];

    bfrag fb0 = *(const bfrag*)&stt[rd][row + 1][q * 8];
    bfrag fb1 = *(const bfrag*)&stt[rd][row + 1][32 + q * 8];
    bfrag ft0 = *(const bfrag*)&stt[rd][srow][q * 8];
    bfrag ft1 = *(const bfrag*)&stt[rd][srow][32 + q * 8];
    bfrag fa0 = *(const bfrag*)&cur.b0;
    bfrag fa1 = *(const bfrag*)&cur.b1;

    f4_t DA[4], DB[4], DT[4];
#pragma unroll
    for (int mt = 0; mt < 4; mt++) {
        DA[mt] = MFMA(WA[mt][0], fa0, cAr[mt], 0, 0, 0);
        DA[mt] = MFMA(WA[mt][1], fa1, DA[mt], 0, 0, 0);
        DB[mt] = MFMA(WB[mt][0], fb0, cBr[mt], 0, 0, 0);
        DB[mt] = MFMA(WB[mt][1], fb1, DB[mt], 0, 0, 0);
        DT[mt] = MFMA(WT[mt][0], ft0, cTr[mt], 0, 0, 0);
        DT[mt] = MFMA(WT[mt][1], ft1, DT[mt], 0, 0, 0);
    }

    // prefetch j+1 (stays in flight across the step barrier)
    if (j < 127) {
        int cjN = flip ? 126 - j : j + 1;
        int ycN = flip ? 127 - j : j;
        const unsigned short* sp = base2 + (size_t)(row * 128 + cjN) * 64 + q * 8;
        nxt.b0 = *(const uint4*)sp;
        nxt.b1 = *(const uint4*)(sp + 32);
#pragma unroll
        for (int mt = 0; mt < 4; mt++)
            nxt.yr[mt] = *(const float4*)&yB[(size_t)(row * 128 + ycN) * 64 + mt * 16 + q * 4];
    }

    // finalize: h = relu(DA + DB*yr + gT*(DT*ys))
#pragma unroll
    for (int mt = 0; mt < 4; mt++) {
        float h0 = fmaxf(DA[mt][0] + DB[mt][0] * cur.yr[mt].x + gT * (DT[mt][0] * ys[mt].x), 0.f);
        float h1 = fmaxf(DA[mt][1] + DB[mt][1] * cur.yr[mt].y + gT * (DT[mt][1] * ys[mt].y), 0.f);
        float h2 = fmaxf(DA[mt][2] + DB[mt][2] * cur.yr[mt].z + gT * (DT[mt][2] * ys[mt].z), 0.f);
        float h3 = fmaxf(DA[mt][3] + DB[mt][3] * cur.yr[mt].w + gT * (DT[mt][3] * ys[mt].w), 0.f);
        *(ushort4*)&stt[wr][row + 1][mt * 16 + q * 4] = pack4(h0, h1, h2, h3);
        *(float4*)&oB[(size_t)(row * 128 + cj) * 64 + mt * 16 + q * 4] =
            make_float4(h0, h1, h2, h3);
    }
}

// grid 32 = d(4) x b(8). 256 threads = 4 waves; wave w owns rows [32w,32w+32)
// as two 16-row groups. 1 wave/SIMD -> 512-VGPR budget: weights, bias C-inits
// and double-buffered prefetch all register-resident.
__global__ __launch_bounds__(256, 1) void k_colscan(
        const float* __restrict__ y2,
        const unsigned short* __restrict__ hs2, const unsigned short* __restrict__ hn2,
        const float* __restrict__ Wc, const float* __restrict__ bc,
        const float* __restrict__ gam,
        float* __restrict__ outD) {
    int bid = blockIdx.x;
    int d = bid >> 3, b = bid & 7;
    int tid = threadIdx.x;
    int wave = tid >> 6, lane = tid & 63, q = lane >> 4, n = lane & 15;
    int r0 = wave * 32 + n;
    int r1 = r0 + 16;
    int down = (d < 2) ? 1 : 0;
    int flip = d & 1;
    const unsigned short* base2 = ((d < 2) ? hs2 : hn2) + (size_t)b * CHW_;
    int kt, ka, kb;
    if (d == 0)      { kt = 2;  ka = 3;  kb = 4;  }
    else if (d == 1) { kt = 5;  ka = 6;  kb = 7;  }
    else if (d == 2) { kt = 10; ka = 11; kb = 12; }
    else             { kt = 13; ka = 14; kb = 15; }
    float g = gam[d];

    bfrag WA[4][2], WB[4][2], WT[4][2];
#pragma unroll
    for (int mt = 0; mt < 4; mt++)
#pragma unroll
        for (int kc = 0; kc < 2; kc++) {
            const float* wa = Wc + (size_t)(ka * 64 + mt * 16 + n) * 64 + kc * 32 + q * 8;
            const float* wb = Wc + (size_t)(kb * 64 + mt * 16 + n) * 64 + kc * 32 + q * 8;
            const float* wt = Wc + (size_t)(kt * 64 + mt * 16 + n) * 64 + kc * 32 + q * 8;
            WA[mt][kc] = packf(*(const float4*)wa, *(const float4*)(wa + 4));
            WB[mt][kc] = packf(*(const float4*)wb, *(const float4*)(wb + 4));
            WT[mt][kc] = packf(*(const float4*)wt, *(const float4*)(wt + 4));
        }
    f4_t cAr[4], cBr[4], cTr[4];
#pragma unroll
    for (int mt = 0; mt < 4; mt++) {
        float4 ta = *(const float4*)&bc[ka * 64 + mt * 16 + q * 4];
        float4 tb = *(const float4*)&bc[kb * 64 + mt * 16 + q * 4];
        float4 tt = *(const float4*)&bc[kt * 64 + mt * 16 + q * 4];
        cAr[mt] = f4_t{ta.x, ta.y, ta.z, ta.w};
        cBr[mt] = f4_t{tb.x, tb.y, tb.z, tb.w};
        cTr[mt] = f4_t{tt.x, tt.y, tt.z, tt.w};
    }

    const float* yB = y2 + (size_t)b * CHW_;
    float* oB = outD + (size_t)d * TOT_ + (size_t)b * CHW_;

    __shared__ __align__(16) unsigned short stt[2][130][72];  // +1 zero pad each end
    for (int idx = tid; idx < 2 * 2 * 72; idx += 256) {
        int buf = idx / 144, hi = (idx / 72) & 1, t = idx % 72;
        stt[buf][hi ? 129 : 0][t] = 0;
    }

    // ---- j = 0 : c0 = relu(base col0), both groups
    int c0 = flip ? 127 : 0;
#pragma unroll
    for (int gi = 0; gi < 2; gi++) {
        int row = gi ? r1 : r0;
        const unsigned short* sp = base2 + (size_t)(row * 128 + c0) * 64 + q * 16;
        uint4 v0 = relu8(*(const uint4*)sp);
        uint4 v1 = relu8(*(const uint4*)(sp + 8));
        *(uint4*)&stt[0][row + 1][q * 16] = v0;
        *(uint4*)&stt[0][row + 1][q * 16 + 8] = v1;
        float* op = oB + (size_t)(row * 128 + c0) * 64 + q * 16;
        unsigned int w8[8] = {v0.x, v0.y, v0.z, v0.w, v1.x, v1.y, v1.z, v1.w};
#pragma unroll
        for (int t = 0; t < 8; t++) {
            op[2 * t]     = b2f((unsigned short)(w8[t] & 0xffffu));
            op[2 * t + 1] = b2f((unsigned short)(w8[t] >> 16));
        }
    }

    int rsh0 = r0 + (down ? -1 : 1); rsh0 = rsh0 < 0 ? 0 : (rsh0 > 127 ? 127 : rsh0);
    int rsh1 = r1 + (down ? -1 : 1); rsh1 = rsh1 < 0 ? 0 : (rsh1 > 127 ? 127 : rsh1);
    int srow0 = down ? r0 : r0 + 2;
    int srow1 = down ? r1 : r1 + 2;
    float gT0 = (down ? (r0 == 0) : (r0 == 127)) ? 0.f : g;
    float gT1 = (down ? (r1 == 0) : (r1 == 127)) ? 0.f : g;

    // prefetch j=1 for both groups
    PrefG P0a, P0b, P1a, P1b;
    {
        int cj1 = flip ? 126 : 1, yc1 = flip ? 127 : 0;
        const unsigned short* sp0 = base2 + (size_t)(r0 * 128 + cj1) * 64 + q * 8;
        P0a.b0 = *(const uint4*)sp0;
        P0a.b1 = *(const uint4*)(sp0 + 32);
        const unsigned short* sp1 = base2 + (size_t)(r1 * 128 + cj1) * 64 + q * 8;
        P0b.b0 = *(const uint4*)sp1;
        P0b.b1 = *(const uint4*)(sp1 + 32);
#pragma unroll
        for (int mt = 0; mt < 4; mt++) {
            P0a.yr[mt] = *(const float4*)&yB[(size_t)(r0 * 128 + yc1) * 64 + mt * 16 + q * 4];
            P0b.yr[mt] = *(const float4*)&yB[(size_t)(r1 * 128 + yc1) * 64 + mt * 16 + q * 4];
        }
    }
    SBAR_LGKM();

    for (int j = 1; j < 127; j += 2) {
        col_group(j, flip, r0, q, rsh0, srow0, gT0, base2, yB, oB, stt, WA, WB, WT, cAr, cBr, cTr, P0a, P1a);
        col_group(j, flip, r1, q, rsh1, srow1, gT1, base2, yB, oB, stt, WA, WB, WT, cAr, cBr, cTr, P0b, P1b);
        SBAR_LGKM();
        col_group(j + 1, flip, r0, q, rsh0, srow0, gT0, base2, yB, oB, stt, WA, WB, WT, cAr, cBr, cTr, P1a, P0a);
        col_group(j + 1, flip, r1, q, rsh1, srow1, gT1, base2, yB, oB, stt, WA, WB, WT, cAr, cBr, cTr, P1b, P0b);
        SBAR_LGKM();
    }
    col_group(127, flip, r0, q, rsh0, srow0, gT0, base2, yB, oB, stt, WA, WB, WT, cAr, cBr, cTr, P0a, P1a);
    col_group(127, flip, r1, q, rsh1, srow1, gT1, base2, yB, oB, stt, WA, WB, WT, cAr, cBr, cTr, P0b, P1b);
}

extern "C" void kernel_launch(void* const* d_in, const int* in_sizes, int n_in,
                              void* d_out, int out_size, void* d_ws, size_t ws_size,
                              hipStream_t stream) {
    const float* x   = (const float*)d_in[0];
    const float* y   = (const float*)d_in[1];
    const float* Wc  = (const float*)d_in[2];
    const float* bc  = (const float*)d_in[3];
    const float* gam = (const float*)d_in[4];
    float* out = (float*)d_out;

    // ws layout (bytes): x2 bf16 (16.8M), y2 fp32 (33.6M), hs2/hn2 bf16 (16.8M ea),
    // outD fp32 x4 dirs (134.2M) => ~218 MB total
    unsigned short* x2 = (unsigned short*)d_ws;
    float* y2 = (float*)d_ws + (size_t)TOT_ / 2;
    unsigned short* hs2 = (unsigned short*)(y2 + (size_t)TOT_);
    unsigned short* hn2 = hs2 + (size_t)TOT_;
    float* outD = (float*)(hn2 + (size_t)TOT_);

    hipLaunchKernelGGL(k_prep, dim3(4096), dim3(256), 0, stream, x, y, y2, x2);
    hipLaunchKernelGGL(k_rowscan, dim3(128), dim3(64), 0, stream, x2, y2, Wc, bc, hs2, hn2);
    hipLaunchKernelGGL(k_colscan, dim3(32), dim3(256), 0, stream, y2, hs2, hn2, Wc, bc, gam, outD);
    hipLaunchKernelGGL(k_tb, dim3(2048), dim3(256), 0, stream,
                       outD, outD + (size_t)TOT_, outD + 2 * (size_t)TOT_,
                       outD + 3 * (size_t)TOT_, out);
}